// Round 10
// baseline (669.301 us; speedup 1.0000x reference)
//
#include <hip/hip_runtime.h>
#include <stdint.h>

typedef __bf16 bf16x8 __attribute__((ext_vector_type(8)));
typedef float f32x4 __attribute__((ext_vector_type(4)));
typedef unsigned short u16x8 __attribute__((ext_vector_type(8)));
typedef unsigned long long ull_t;
typedef unsigned short ushort_t;

#define DEV __device__ __forceinline__

DEV unsigned short f2bf(float f) {
  __bf16 b = (__bf16)f;
  return __builtin_bit_cast(unsigned short, b);
}

DEV float bf2f(unsigned short b) { return __uint_as_float((unsigned int)b << 16); }

DEV f32x4 zero4() { f32x4 z = {0.f, 0.f, 0.f, 0.f}; return z; }

DEV float softplusf(float v) { return (v > 15.f) ? v : log1pf(expf(v)); }

// Pack W[K][Ncols] (f32 row-major) -> fragment-major bf16 (split-4 k-layout).
// permk: remap stored k -> true W row within each 64-group (compensates hid col-permute)
__global__ void pack_weight(const float* __restrict__ W, unsigned short* __restrict__ P,
                            int K, int Ncols, int permk) {
  int idx = blockIdx.x * 256 + threadIdx.x;
  if (idx >= K * Ncols) return;
  int j = idx & 7;
  int lane = (idx >> 3) & 63;
  int rest = idx >> 9;
  int NT = Ncols >> 4;
  int nt = rest % NT;
  int kt = rest / NT;
  int k = kt * 32 + ((j >> 2) * 16) + ((lane >> 4) * 4) + (j & 3);
  if (permk) k = (k & ~63) | ((k & 3) << 4) | ((k >> 2) & 15);
  int col = nt * 16 + (lane & 15);
  P[idx] = f2bf(W[(size_t)k * Ncols + col]);
}

__global__ void k_cvt_bf16(const float* __restrict__ in, ushort_t* __restrict__ out,
                           int n4) {
  int i = blockIdx.x * 256 + threadIdx.x;
  if (i >= n4) return;
  float4 v = *(const float4*)(in + (size_t)i * 4);
  ushort4 b;
  b.x = f2bf(v.x); b.y = f2bf(v.y); b.z = f2bf(v.z); b.w = f2bf(v.w);
  *(ushort4*)(out + (size_t)i * 4) = b;
}

__global__ void k_deg(const int* __restrict__ dst, int* __restrict__ degi, int E) {
  int i = blockIdx.x * 256 + threadIdx.x;
  if (i < E) atomicAdd(&degi[dst[i]], 1);
}

__global__ void k_dis(const int* __restrict__ degi, float* __restrict__ dis, int n) {
  int i = blockIdx.x * 256 + threadIdx.x;
  if (i < n) dis[i] = rsqrtf((float)degi[i] + 1.0f);
}

// Single-block exclusive scan: ptr[0..n] from degi[0..n-1].
__global__ __launch_bounds__(1024) void k_scan(const int* __restrict__ degi,
                                               int* __restrict__ ptr, int n) {
  __shared__ int part[1024];
  const int tid = threadIdx.x;
  const int chunk = (n + 1023) / 1024;
  const int b = tid * chunk;
  const int e2 = min(n, b + chunk);
  int s = 0;
  for (int i = b; i < e2; ++i) s += degi[i];
  part[tid] = s;
  __syncthreads();
  for (int off = 1; off < 1024; off <<= 1) {
    int val = (tid >= off) ? part[tid - off] : 0;
    __syncthreads();
    part[tid] += val;
    __syncthreads();
  }
  int run = (tid == 0) ? 0 : part[tid - 1];
  for (int i = b; i < e2; ++i) {
    ptr[i] = run;
    run += degi[i];
  }
  if (tid == 1023) ptr[n] = run;
}

// Counting-sort fill: edges grouped by dst; store (src, dis[src]*dis[dst]).
__global__ void k_fill(const int* __restrict__ srcs, const int* __restrict__ dsts,
                       const int* __restrict__ ptr, const float* __restrict__ dis,
                       int* __restrict__ fillc,
                       int2* __restrict__ sc_s, int* __restrict__ dst_s,
                       int* __restrict__ perm_s, int E) {
  int e = blockIdx.x * 256 + threadIdx.x;
  if (e >= E) return;
  int d = dsts[e];
  int s = srcs[e];
  int pos = ptr[d] + atomicAdd(&fillc[d], 1);
  float c = dis[s] * dis[d];
  sc_s[pos] = make_int2(s, __float_as_int(c));
  dst_s[pos] = d;
  perm_s[pos] = e;
}

// Per-node CSR gather: acc = sum_{e in N(v)} feat[src_e]*c_e, 4-deep unrolled.
// FINALIZE: out = relu(acc + hw[v]*dis[v]^2 + bias).  INBF16: feat/hw are bf16.
template <int COLS, bool FINALIZE, bool INBF16>
__global__ __launch_bounds__(256) void k_gather_agg(
    const void* __restrict__ featv, const int2* __restrict__ sc,
    const int* __restrict__ ptr, const float* __restrict__ dis,
    const void* __restrict__ hwv, const float* __restrict__ bias,
    float* __restrict__ out, int n) {
  constexpr int V = COLS / 64;
  const int v = blockIdx.x * 4 + (threadIdx.x >> 6);
  if (v >= n) return;
  const int lane = threadIdx.x & 63;
  const int beg = ptr[v], end = ptr[v + 1];

  auto loadrow = [&](int s, float* f) {
    if constexpr (INBF16) {
      const ushort_t* feat = (const ushort_t*)featv;
      if constexpr (V == 4) {
        ushort4 u = *(const ushort4*)(feat + (size_t)s * COLS + lane * 4);
        f[0] = bf2f(u.x); f[1] = bf2f(u.y); f[2] = bf2f(u.z); f[3] = bf2f(u.w);
      } else {
        f[0] = bf2f(feat[(size_t)s * COLS + lane]);
      }
    } else {
      const float* feat = (const float*)featv;
      if constexpr (V == 4) {
        float4 q = *(const float4*)(feat + (size_t)s * COLS + lane * 4);
        f[0] = q.x; f[1] = q.y; f[2] = q.z; f[3] = q.w;
      } else {
        f[0] = feat[(size_t)s * COLS + lane];
      }
    }
  };

  float acc[V];
#pragma unroll
  for (int i = 0; i < V; ++i) acc[i] = 0.f;
  const int cnt = end - beg;
  const int2* scp = sc + beg;
  int i = 0;
  for (; i + 4 <= cnt; i += 4) {
    int2 s0 = scp[i], s1 = scp[i + 1], s2 = scp[i + 2], s3 = scp[i + 3];
    float f0[V], f1[V], f2[V], f3[V];
    loadrow(s0.x, f0); loadrow(s1.x, f1); loadrow(s2.x, f2); loadrow(s3.x, f3);
    float c0 = __int_as_float(s0.y), c1 = __int_as_float(s1.y);
    float c2 = __int_as_float(s2.y), c3 = __int_as_float(s3.y);
#pragma unroll
    for (int j = 0; j < V; ++j)
      acc[j] += f0[j] * c0 + f1[j] * c1 + f2[j] * c2 + f3[j] * c3;
  }
  for (; i < cnt; ++i) {
    int2 s0 = scp[i];
    float c0 = __int_as_float(s0.y);
    float f0[V];
    loadrow(s0.x, f0);
#pragma unroll
    for (int j = 0; j < V; ++j) acc[j] += f0[j] * c0;
  }
  float* op = out + (size_t)v * COLS + lane * V;
  if constexpr (FINALIZE) {
    const float dv = dis[v];
    float d2 = dv * dv;
    float h[V];
    if constexpr (INBF16) {
      const ushort_t* hw = (const ushort_t*)hwv;
      if constexpr (V == 4) {
        ushort4 u = *(const ushort4*)(hw + (size_t)v * COLS + lane * 4);
        h[0] = bf2f(u.x); h[1] = bf2f(u.y); h[2] = bf2f(u.z); h[3] = bf2f(u.w);
      } else {
        h[0] = bf2f(hw[(size_t)v * COLS + lane]);
      }
    } else {
      const float* hw = (const float*)hwv;
      if constexpr (V == 4) {
        float4 q = *(const float4*)(hw + (size_t)v * COLS + lane * 4);
        h[0] = q.x; h[1] = q.y; h[2] = q.z; h[3] = q.w;
      } else {
        h[0] = hw[(size_t)v * COLS + lane];
      }
    }
#pragma unroll
    for (int i2 = 0; i2 < V; ++i2)
      acc[i2] = fmaxf(acc[i2] + h[i2] * d2 + bias[lane * V + i2], 0.f);
  }
  if constexpr (V == 4) {
    *(float4*)op = make_float4(acc[0], acc[1], acc[2], acc[3]);
  } else {
    op[0] = acc[0];
  }
}

// Generic node GEMM: out[r,:NOUT] = inA[r,:K] (+inB[r,:K]*dis[r]^2) @ Wp (+bias)
template <int K, int NOUT, bool COMPOSE, bool RELUBIAS, bool OUTBF16,
          bool ADDBIAS, bool PERMOUT>
__global__ __launch_bounds__(256, 2) void gcn_gemm(
    const float* __restrict__ inA, const float* __restrict__ inB,
    const float* __restrict__ dis,
    const unsigned short* __restrict__ Wp, const float* __restrict__ bias,
    void* __restrict__ outv, int out_stride, int nrows) {
  constexpr int NT = NOUT / 16;
  constexpr int NTW = NOUT / 64;
  __shared__ unsigned short s_in[64 * K];
  const int tid = threadIdx.x;
  const int r0 = blockIdx.x * 64;

  constexpr int C4R = K / 4;
  for (int idx = tid; idx < 64 * C4R; idx += 256) {
    int row = idx / C4R;
    int rem = idx - row * C4R;
    int grow = r0 + row;
    float4 v = make_float4(0.f, 0.f, 0.f, 0.f);
    if (grow < nrows) {
      v = *(const float4*)&inA[(size_t)grow * K + rem * 4];
      if constexpr (COMPOSE) {
        float d = dis[grow];
        d *= d;
        float4 w2 = *(const float4*)&inB[(size_t)grow * K + rem * 4];
        v.x += w2.x * d; v.y += w2.y * d; v.z += w2.z * d; v.w += w2.w * d;
      }
    }
    ushort4 b;
    b.x = f2bf(v.x); b.y = f2bf(v.y); b.z = f2bf(v.z); b.w = f2bf(v.w);
    *(ushort4*)&s_in[row * K + ((rem ^ (row & 7)) * 4)] = b;
  }
  __syncthreads();

  const int lane = tid & 63, wid = tid >> 6;
  const int lr = lane & 15, lg = lane >> 4;
  f32x4 acc[4][NTW];
#pragma unroll
  for (int m = 0; m < 4; ++m)
#pragma unroll
    for (int n2 = 0; n2 < NTW; ++n2) acc[m][n2] = zero4();

#pragma unroll
  for (int kt = 0; kt < K / 32; ++kt) {
    bf16x8 a[4];
#pragma unroll
    for (int m = 0; m < 4; ++m) {
      int rA = m * 16 + lr;
      int c1 = (kt * 8 + lg) ^ (rA & 7);
      int c2 = (kt * 8 + lg + 4) ^ (rA & 7);
      union { bf16x8 v; ull_t q[2]; } u;
      u.q[0] = *(const ull_t*)&s_in[rA * K + c1 * 4];
      u.q[1] = *(const ull_t*)&s_in[rA * K + c2 * 4];
      a[m] = u.v;
    }
#pragma unroll
    for (int n2 = 0; n2 < NTW; ++n2) {
      int nt = wid * NTW + n2;
      bf16x8 b = *(const bf16x8*)&Wp[(((kt * NT + nt) * 64 + lane) * 8)];
#pragma unroll
      for (int m = 0; m < 4; ++m)
        acc[m][n2] = __builtin_amdgcn_mfma_f32_16x16x32_bf16(a[m], b, acc[m][n2], 0, 0, 0);
    }
  }

#pragma unroll
  for (int n2 = 0; n2 < NTW; ++n2) {
    int col = (wid * NTW + n2) * 16 + lr;
    float bv = 0.f;
    if (RELUBIAS || ADDBIAS) bv = bias[col];
    int colw = col;
    if (PERMOUT) colw = (col & ~63) | ((col & 15) << 2) | ((col >> 4) & 3);
#pragma unroll
    for (int m = 0; m < 4; ++m) {
#pragma unroll
      for (int r = 0; r < 4; ++r) {
        int grow = r0 + m * 16 + lg * 4 + r;
        if (grow < nrows) {
          float v = acc[m][n2][r];
          if (RELUBIAS) v = fmaxf(v + bv, 0.f);
          else if (ADDBIAS) v = v + bv;
          if constexpr (OUTBF16) {
            ((ushort_t*)outv)[(size_t)grow * out_stride + colw] = f2bf(v);
          } else {
            ((float*)outv)[(size_t)grow * out_stride + colw] = v;
          }
        }
      }
    }
  }
}

// Fused EdgeConv, dst-sorted edges, dst-term hoisted. De-barriered:
// index arrays read directly from global (L2-hot); per-wave ballot mask.
__global__ __launch_bounds__(512, 4) void k_edgeconv(
    const ushort_t* __restrict__ xb, const float* __restrict__ ea,
    const int2* __restrict__ sc_s, const int* __restrict__ dst_s,
    const int* __restrict__ perm_s,
    const unsigned short* __restrict__ W1p, const float* __restrict__ h1p,
    const unsigned short* __restrict__ W2p, const float* __restrict__ b2,
    float* __restrict__ h2, int E) {
  __shared__ unsigned short s_buf[256 * 72];  // 36864 B, aliased across phases
  const int tid = threadIdx.x;
  const int e0 = blockIdx.x * 64;
  const int lane = tid & 63, wid = tid >> 6;
  const bool full = (e0 + 64 <= E);

  // Per-wave dst-change mask (no LDS, no barrier).
  int myd = (full || e0 + lane < E) ? dst_s[e0 + lane] : 0;
  int prevd = (lane > 0 && (full || e0 + lane - 1 < E)) ? dst_s[e0 + lane - 1] : 0;
  ull_t mask64 = __ballot(lane > 0 && myd != prevd);

  // Stage [x_src | ea] bf16 into s_buf[row][128], chunk-swizzled.
#pragma unroll
  for (int seg = 0; seg < 2; ++seg) {
#pragma unroll
    for (int it = 0; it < 2; ++it) {
      int idx = it * 512 + tid;
      int ei = idx >> 4;
      int q = idx & 15;
      int e = e0 + ei;
      ushort4 b;
      if (seg == 0) {
        int src = (full || e < E) ? sc_s[e].x : 0;
        b = *(const ushort4*)(xb + (unsigned)src * 64u + q * 4);
      } else {
        float4 v = make_float4(0.f, 0.f, 0.f, 0.f);
        if (full || e < E) {
          int pe = perm_s[e];
          v = *(const float4*)(ea + (unsigned)pe * 64u + q * 4);
        }
        b.x = f2bf(v.x); b.y = f2bf(v.y); b.z = f2bf(v.z); b.w = f2bf(v.w);
      }
      int chunk = (seg * 16 + q) ^ (ei & 7);
      *(ushort4*)&s_buf[ei * 128 + chunk * 4] = b;
    }
  }
  __syncthreads();

  const int wr = wid >> 2;   // 0..1 : row block (32 rows)
  const int wc = wid & 3;    // 0..3 : col block (64 cols)
  const int lr = lane & 15, lg = lane >> 4;
  f32x4 acc[2][4];
#pragma unroll
  for (int m = 0; m < 2; ++m)
#pragma unroll
    for (int n2 = 0; n2 < 4; ++n2) acc[m][n2] = zero4();

  // GEMM1: K=128 -> hidden 256
#pragma unroll
  for (int kt = 0; kt < 4; ++kt) {
    bf16x8 a[2];
#pragma unroll
    for (int m = 0; m < 2; ++m) {
      int rA = wr * 32 + m * 16 + lr;
      int rr = rA & 7;
      union { bf16x8 v; ull_t q[2]; } u;
      u.q[0] = *(const ull_t*)&s_buf[rA * 128 + ((kt * 8 + lg) ^ rr) * 4];
      u.q[1] = *(const ull_t*)&s_buf[rA * 128 + ((kt * 8 + lg + 4) ^ rr) * 4];
      a[m] = u.v;
    }
#pragma unroll
    for (int n2 = 0; n2 < 4; ++n2) {
      int nt = wc * 4 + n2;
      int boff = ((kt * 16 + nt) * 64 + lane) * 8;
      bf16x8 b = *(const bf16x8*)&W1p[boff];
#pragma unroll
      for (int m = 0; m < 2; ++m)
        acc[m][n2] = __builtin_amdgcn_mfma_f32_16x16x32_bf16(a[m], b, acc[m][n2], 0, 0, 0);
    }
  }
  __syncthreads();  // all GEMM1 reads of s_buf done; safe to overwrite

  // hid = relu(acc1 + h1[dst]) bf16 -> s_buf[row][256] COL-PERMUTED, b64 writes.
#pragma unroll
  for (int m = 0; m < 2; ++m) {
#pragma unroll
    for (int r = 0; r < 4; ++r) {
      int row = wr * 32 + m * 16 + lg * 4 + r;
      int drow = (full || e0 + row < E) ? dst_s[e0 + row] : 0;
      float4 hq = *(const float4*)(h1p + (size_t)(unsigned)drow * 256u +
                                   wc * 64 + lr * 4);
      union { ushort_t h[4]; ull_t q; } pk;
      pk.h[0] = f2bf(fmaxf(acc[m][0][r] + hq.x, 0.f));
      pk.h[1] = f2bf(fmaxf(acc[m][1][r] + hq.y, 0.f));
      pk.h[2] = f2bf(fmaxf(acc[m][2][r] + hq.z, 0.f));
      pk.h[3] = f2bf(fmaxf(acc[m][3][r] + hq.w, 0.f));
      int chunk = (wc * 16 + lr) ^ (row & 7);
      *(ull_t*)&s_buf[row * 256 + chunk * 4] = pk.q;
    }
  }
  __syncthreads();

  // GEMM2: K=256 (k-space is the permuted hid layout; W2p pack compensates)
#pragma unroll
  for (int m = 0; m < 2; ++m)
#pragma unroll
    for (int n2 = 0; n2 < 4; ++n2) acc[m][n2] = zero4();
#pragma unroll
  for (int kt = 0; kt < 8; ++kt) {
    bf16x8 a[2];
#pragma unroll
    for (int m = 0; m < 2; ++m) {
      int rA = wr * 32 + m * 16 + lr;
      int rr = rA & 7;
      union { bf16x8 v; ull_t q[2]; } u;
      u.q[0] = *(const ull_t*)&s_buf[rA * 256 + ((kt * 8 + lg) ^ rr) * 4];
      u.q[1] = *(const ull_t*)&s_buf[rA * 256 + ((kt * 8 + lg + 4) ^ rr) * 4];
      a[m] = u.v;
    }
#pragma unroll
    for (int n2 = 0; n2 < 4; ++n2) {
      int nt = wc * 4 + n2;
      int boff = ((kt * 16 + nt) * 64 + lane) * 8;
      bf16x8 b = *(const bf16x8*)&W2p[boff];
#pragma unroll
      for (int m = 0; m < 2; ++m)
        acc[m][n2] = __builtin_amdgcn_mfma_f32_16x16x32_bf16(a[m], b, acc[m][n2], 0, 0, 0);
    }
  }
  __syncthreads();  // all GEMM2 reads done; safe to overwrite

  // m = relu(acc2 + b2) -> TRANSPOSED [col][72] as packed b64 (4 rows/write)
#pragma unroll
  for (int n2 = 0; n2 < 4; ++n2) {
    int col = (wc * 4 + n2) * 16 + lr;
    float bv = b2[col];
#pragma unroll
    for (int m = 0; m < 2; ++m) {
      int rbase = wr * 32 + m * 16 + lg * 4;
      union { ushort_t h[4]; ull_t q; } pk;
#pragma unroll
      for (int r = 0; r < 4; ++r) {
        int row = rbase + r;
        float v = (full || e0 + row < E) ? fmaxf(acc[m][n2][r] + bv, 0.f) : 0.f;
        pk.h[r] = f2bf(v);
      }
      *(ull_t*)&s_buf[col * 72 + rbase] = pk.q;
    }
  }
  __syncthreads();

  // Segmented max scan in u16 domain: thread = (row-half, column).
  {
    const int col = tid & 255;
    const int half = tid >> 8;
    const int rbeg = half * 32;
    const unsigned int mask = (unsigned int)(mask64 >> rbeg);
    unsigned int run = 0;
    int segstart = rbeg;
#pragma unroll
    for (int i = 0; i < 4; ++i) {
      u16x8 pack = *(const u16x8*)&s_buf[col * 72 + rbeg + i * 8];
#pragma unroll
      for (int r2 = 0; r2 < 8; ++r2) {
        int rloc = i * 8 + r2;
        if (mask & (1u << rloc)) {
          if (run > 0)
            atomicMax((int*)h2 + ((unsigned)dst_s[e0 + segstart] * 512u + 256u + col),
                      (int)(run << 16));
          run = 0;
          segstart = rbeg + rloc;
        }
        run = max(run, (unsigned int)pack[r2]);
      }
    }
    if (run > 0)
      atomicMax((int*)h2 + ((unsigned)dst_s[e0 + segstart] * 512u + 256u + col),
                (int)(run << 16));
  }
}

// Head MLP: wave-per-node, weights (except W2) staged in LDS.
__global__ __launch_bounds__(256) void k_head(
    const float* __restrict__ x, const float* __restrict__ out3,
    const float* __restrict__ W1, const float* __restrict__ b1,
    const float* __restrict__ W2, const float* __restrict__ b2,
    const float* __restrict__ W3, const float* __restrict__ b3,
    const float* __restrict__ W4, const float* __restrict__ b4,
    float* __restrict__ out, int n) {
  __shared__ float sW1[128 * 64];
  __shared__ float sW3[128 * 32];
  __shared__ float sW4[32 * 2];
  __shared__ float sb1[64], sb2[128], sb3[32], sb4[2];
  __shared__ float sbuf[4][352];
  const int tid = threadIdx.x;
  for (int i = tid; i < 128 * 64; i += 256) sW1[i] = W1[i];
  for (int i = tid; i < 128 * 32; i += 256) sW3[i] = W3[i];
  if (tid < 64) sW4[tid] = W4[tid];
  if (tid < 64) sb1[tid] = b1[tid];
  if (tid < 128) sb2[tid] = b2[tid];
  if (tid < 32) sb3[tid] = b3[tid];
  if (tid < 2) sb4[tid] = b4[tid];
  __syncthreads();
  const int wid = tid >> 6, lane = tid & 63;
  float* B = sbuf[wid];
  const int per = gridDim.x * 4;
  const int iters = (n + per - 1) / per;
  for (int it = 0; it < iters; ++it) {
    const int node = it * per + blockIdx.x * 4 + wid;
    const bool act = node < n;
    if (act) {
      B[lane] = x[(size_t)node * 64 + lane];
      B[64 + lane] = out3[(size_t)node * 64 + lane];
    }
    __syncthreads();
    if (act) {
      float o = sb1[lane];
#pragma unroll 8
      for (int k = 0; k < 128; ++k) o += B[k] * sW1[k * 64 + lane];
      B[128 + lane] = softplusf(o);
    }
    __syncthreads();
    if (act) {
      float o0 = sb2[lane], o1 = sb2[64 + lane];
#pragma unroll 8
      for (int k = 0; k < 64; ++k) {
        float v = B[128 + k];
        o0 += v * W2[k * 128 + lane];
        o1 += v * W2[k * 128 + 64 + lane];
      }
      B[192 + lane] = softplusf(o0);
      B[256 + lane] = softplusf(o1);
    }
    __syncthreads();
    if (act && lane < 32) {
      float o = sb3[lane];
#pragma unroll 8
      for (int k = 0; k < 128; ++k) o += B[192 + k] * sW3[k * 32 + lane];
      B[320 + lane] = softplusf(o);
    }
    __syncthreads();
    if (act && lane < 2) {
      float o = sb4[lane];
#pragma unroll
      for (int k = 0; k < 32; ++k) o += B[320 + k] * sW4[k * 2 + lane];
      out[(size_t)lane * n + node] = o;
    }
    __syncthreads();
  }
}

static inline size_t alignup(size_t v) { return (v + 255) & ~(size_t)255; }

extern "C" void kernel_launch(void* const* d_in, const int* in_sizes, int n_in,
                              void* d_out, int out_size, void* d_ws, size_t ws_size,
                              hipStream_t stream) {
  const float* x = (const float*)d_in[0];
  const int* ei = (const int*)d_in[1];
  const float* ea = (const float*)d_in[2];
  const float* c1W = (const float*)d_in[3];
  const float* c1b = (const float*)d_in[4];
  const float* eW1 = (const float*)d_in[5];
  const float* eb1 = (const float*)d_in[6];
  const float* eW2 = (const float*)d_in[7];
  const float* eb2 = (const float*)d_in[8];
  const float* c2W = (const float*)d_in[9];
  const float* c2b = (const float*)d_in[10];
  const float* c3W = (const float*)d_in[11];
  const float* c3b = (const float*)d_in[12];
  const float* l1W = (const float*)d_in[13];
  const float* l1b = (const float*)d_in[14];
  const float* l2W = (const float*)d_in[15];
  const float* l2b = (const float*)d_in[16];
  const float* l3W = (const float*)d_in[17];
  const float* l3b = (const float*)d_in[18];
  const float* l4W = (const float*)d_in[19];
  const float* l4b = (const float*)d_in[20];
  const int n = in_sizes[0] / 64;
  const int E = in_sizes[1] / 2;
  const int* srcs = ei;
  const int* dsts = ei + E;

  char* w = (char*)d_ws;
  auto alloc = [&](size_t bytes) {
    char* p = w;
    w += alignup(bytes);
    return p;
  };
  float* dis = (float*)alloc((size_t)n * 4);
  int* degi = (int*)alloc((size_t)n * 4);
  int* ptr = (int*)alloc((size_t)(n + 1) * 4);
  int* fillc = (int*)alloc((size_t)n * 4);
  int2* sc_s = (int2*)alloc((size_t)E * 8);
  int* dst_s = (int*)alloc((size_t)E * 4);
  int* perm_s = (int*)alloc((size_t)E * 4);
  float* agg1 = (float*)alloc((size_t)n * 64 * 4);
  float* h2 = (float*)alloc((size_t)n * 512 * 4);          // [out1 | out_e1] f32
  ushort_t* hw2b = (ushort_t*)alloc((size_t)n * 256 * 2);  // bf16
  float* out2 = (float*)alloc((size_t)n * 256 * 4);
  ushort_t* hw3b = (ushort_t*)alloc((size_t)n * 64 * 2);   // bf16
  float* out3 = (float*)alloc((size_t)n * 64 * 4);
  ushort_t* xb = (ushort_t*)alloc((size_t)n * 64 * 2);     // x as bf16
  float* h1p = (float*)alloc((size_t)n * 256 * 4);         // dst-term, frag order
  unsigned short* p_c1 = (unsigned short*)alloc(64 * 256 * 2);
  unsigned short* p_e1a = (unsigned short*)alloc(64 * 256 * 2);   // W1 rows 0..63
  unsigned short* p_e1b = (unsigned short*)alloc(128 * 256 * 2);  // W1 rows 64..191
  unsigned short* p_e2 = (unsigned short*)alloc(256 * 256 * 2);   // PERMK
  unsigned short* p_c2 = (unsigned short*)alloc(512 * 256 * 2);
  unsigned short* p_c3 = (unsigned short*)alloc(256 * 64 * 2);

  hipMemsetAsync(degi, 0, (size_t)n * 4, stream);
  hipMemsetAsync(fillc, 0, (size_t)n * 4, stream);
  hipMemsetAsync(h2, 0, (size_t)n * 512 * 4, stream);

  pack_weight<<<(64 * 256) / 256, 256, 0, stream>>>(c1W, p_c1, 64, 256, 0);
  pack_weight<<<(64 * 256) / 256, 256, 0, stream>>>(eW1, p_e1a, 64, 256, 0);
  pack_weight<<<(128 * 256) / 256, 256, 0, stream>>>(eW1 + 64 * 256, p_e1b, 128, 256, 0);
  pack_weight<<<(256 * 256) / 256, 256, 0, stream>>>(eW2, p_e2, 256, 256, 1);
  pack_weight<<<(512 * 256) / 256, 256, 0, stream>>>(c2W, p_c2, 512, 256, 0);
  pack_weight<<<(256 * 64) / 256, 256, 0, stream>>>(c3W, p_c3, 256, 64, 0);
  k_cvt_bf16<<<(n * 16 + 255) / 256, 256, 0, stream>>>(x, xb, n * 16);

  // CSR build
  k_deg<<<(E + 255) / 256, 256, 0, stream>>>(dsts, degi, E);
  k_dis<<<(n + 255) / 256, 256, 0, stream>>>(degi, dis, n);
  k_scan<<<1, 1024, 0, stream>>>(degi, ptr, n);
  k_fill<<<(E + 255) / 256, 256, 0, stream>>>(srcs, dsts, ptr, dis, fillc,
                                              sc_s, dst_s, perm_s, E);

  const int ablocks = (n + 3) / 4;
  const int gblocks = (n + 63) / 64;

  // h1 = x @ W1[0:64] + b1, stored f32 in frag col order
  gcn_gemm<64, 256, false, false, false, true, true><<<gblocks, 256, 0, stream>>>(
      x, nullptr, nullptr, p_e1a, eb1, h1p, 256, n);

  // conv1: gather-aggregate xb (64 ch, bf16), then GEMM with fused self-loop term
  k_gather_agg<64, false, true><<<ablocks, 256, 0, stream>>>(
      xb, sc_s, ptr, dis, nullptr, nullptr, agg1, n);
  gcn_gemm<64, 256, true, true, false, false, false><<<gblocks, 256, 0, stream>>>(
      agg1, x, dis, p_c1, c1b, h2, 512, n);

  // EdgeConv -> h2[:, 256:512]
  k_edgeconv<<<(E + 63) / 64, 512, 0, stream>>>(xb, ea, sc_s, dst_s, perm_s,
                                                p_e1b, h1p, p_e2, eb2, h2, E);

  // conv2: matmul (bf16 out) then gather-aggregate (256 ch bf16) + fused finalize
  gcn_gemm<512, 256, false, false, true, false, false><<<gblocks, 256, 0, stream>>>(
      h2, nullptr, nullptr, p_c2, nullptr, hw2b, 256, n);
  k_gather_agg<256, true, true><<<ablocks, 256, 0, stream>>>(
      hw2b, sc_s, ptr, dis, hw2b, c2b, out2, n);

  // conv3: matmul (bf16 out) then gather-aggregate (64 ch bf16) + fused finalize
  gcn_gemm<256, 64, false, false, true, false, false><<<gblocks, 256, 0, stream>>>(
      out2, nullptr, nullptr, p_c3, nullptr, hw3b, 64, n);
  k_gather_agg<64, true, true><<<ablocks, 256, 0, stream>>>(
      hw3b, sc_s, ptr, dis, hw3b, c3b, out3, n);

  k_head<<<1250, 256, 0, stream>>>(x, out3, l1W, l1b, l2W, l2b, l3W, l3b, l4W, l4b,
                                   (float*)d_out, n);
}

// Round 11
// 599.518 us; speedup vs baseline: 1.1164x; 1.1164x over previous
//
#include <hip/hip_runtime.h>
#include <stdint.h>

typedef __bf16 bf16x8 __attribute__((ext_vector_type(8)));
typedef float f32x4 __attribute__((ext_vector_type(4)));
typedef unsigned short u16x8 __attribute__((ext_vector_type(8)));
typedef unsigned long long ull_t;
typedef unsigned short ushort_t;

#define DEV __device__ __forceinline__

DEV unsigned short f2bf(float f) {
  __bf16 b = (__bf16)f;
  return __builtin_bit_cast(unsigned short, b);
}

DEV float bf2f(unsigned short b) { return __uint_as_float((unsigned int)b << 16); }

DEV f32x4 zero4() { f32x4 z = {0.f, 0.f, 0.f, 0.f}; return z; }

DEV float softplusf(float v) { return (v > 15.f) ? v : log1pf(expf(v)); }

// Pack W[K][Ncols] (f32 row-major) -> fragment-major bf16 (split-4 k-layout).
// permk: remap stored k -> true W row within each 64-group (compensates hid col-permute)
__global__ void pack_weight(const float* __restrict__ W, unsigned short* __restrict__ P,
                            int K, int Ncols, int permk) {
  int idx = blockIdx.x * 256 + threadIdx.x;
  if (idx >= K * Ncols) return;
  int j = idx & 7;
  int lane = (idx >> 3) & 63;
  int rest = idx >> 9;
  int NT = Ncols >> 4;
  int nt = rest % NT;
  int kt = rest / NT;
  int k = kt * 32 + ((j >> 2) * 16) + ((lane >> 4) * 4) + (j & 3);
  if (permk) k = (k & ~63) | ((k & 3) << 4) | ((k >> 2) & 15);
  int col = nt * 16 + (lane & 15);
  P[idx] = f2bf(W[(size_t)k * Ncols + col]);
}

__global__ void k_deg(const int* __restrict__ dst, int* __restrict__ degi, int E) {
  int i = blockIdx.x * 256 + threadIdx.x;
  if (i < E) atomicAdd(&degi[dst[i]], 1);
}

__global__ void k_dis(const int* __restrict__ degi, float* __restrict__ dis, int n) {
  int i = blockIdx.x * 256 + threadIdx.x;
  if (i < n) dis[i] = rsqrtf((float)degi[i] + 1.0f);
}

// Single-block exclusive scan: ptr[0..n] from degi[0..n-1].
__global__ __launch_bounds__(1024) void k_scan(const int* __restrict__ degi,
                                               int* __restrict__ ptr, int n) {
  __shared__ int part[1024];
  const int tid = threadIdx.x;
  const int chunk = (n + 1023) / 1024;
  const int b = tid * chunk;
  const int e2 = min(n, b + chunk);
  int s = 0;
  for (int i = b; i < e2; ++i) s += degi[i];
  part[tid] = s;
  __syncthreads();
  for (int off = 1; off < 1024; off <<= 1) {
    int val = (tid >= off) ? part[tid - off] : 0;
    __syncthreads();
    part[tid] += val;
    __syncthreads();
  }
  int run = (tid == 0) ? 0 : part[tid - 1];
  for (int i = b; i < e2; ++i) {
    ptr[i] = run;
    run += degi[i];
  }
  if (tid == 1023) ptr[n] = run;
}

// Counting-sort fill: edges grouped by dst; store (src, dis[src]*dis[dst]).
__global__ void k_fill(const int* __restrict__ srcs, const int* __restrict__ dsts,
                       const int* __restrict__ ptr, const float* __restrict__ dis,
                       int* __restrict__ fillc,
                       int2* __restrict__ sc_s, int* __restrict__ dst_s,
                       int* __restrict__ perm_s, int E) {
  int e = blockIdx.x * 256 + threadIdx.x;
  if (e >= E) return;
  int d = dsts[e];
  int s = srcs[e];
  int pos = ptr[d] + atomicAdd(&fillc[d], 1);
  float c = dis[s] * dis[d];
  sc_s[pos] = make_int2(s, __float_as_int(c));
  dst_s[pos] = d;
  perm_s[pos] = e;
}

// Per-node CSR gather: acc = sum_{e in N(v)} feat[src_e]*c_e, 4-deep unrolled.
// FINALIZE: out = relu(acc + hw[v]*dis[v]^2 + bias).  INBF16: feat/hw are bf16.
template <int COLS, bool FINALIZE, bool INBF16>
__global__ __launch_bounds__(256) void k_gather_agg(
    const void* __restrict__ featv, const int2* __restrict__ sc,
    const int* __restrict__ ptr, const float* __restrict__ dis,
    const void* __restrict__ hwv, const float* __restrict__ bias,
    float* __restrict__ out, int n) {
  constexpr int V = COLS / 64;
  const int v = blockIdx.x * 4 + (threadIdx.x >> 6);
  if (v >= n) return;
  const int lane = threadIdx.x & 63;
  const int beg = ptr[v], end = ptr[v + 1];

  auto loadrow = [&](int s, float* f) {
    if constexpr (INBF16) {
      const ushort_t* feat = (const ushort_t*)featv;
      if constexpr (V == 4) {
        ushort4 u = *(const ushort4*)(feat + (size_t)s * COLS + lane * 4);
        f[0] = bf2f(u.x); f[1] = bf2f(u.y); f[2] = bf2f(u.z); f[3] = bf2f(u.w);
      } else {
        f[0] = bf2f(feat[(size_t)s * COLS + lane]);
      }
    } else {
      const float* feat = (const float*)featv;
      if constexpr (V == 4) {
        float4 q = *(const float4*)(feat + (size_t)s * COLS + lane * 4);
        f[0] = q.x; f[1] = q.y; f[2] = q.z; f[3] = q.w;
      } else {
        f[0] = feat[(size_t)s * COLS + lane];
      }
    }
  };

  float acc[V];
#pragma unroll
  for (int i = 0; i < V; ++i) acc[i] = 0.f;
  const int cnt = end - beg;
  const int2* scp = sc + beg;
  int i = 0;
  for (; i + 4 <= cnt; i += 4) {
    int2 s0 = scp[i], s1 = scp[i + 1], s2 = scp[i + 2], s3 = scp[i + 3];
    float f0[V], f1[V], f2[V], f3[V];
    loadrow(s0.x, f0); loadrow(s1.x, f1); loadrow(s2.x, f2); loadrow(s3.x, f3);
    float c0 = __int_as_float(s0.y), c1 = __int_as_float(s1.y);
    float c2 = __int_as_float(s2.y), c3 = __int_as_float(s3.y);
#pragma unroll
    for (int j = 0; j < V; ++j)
      acc[j] += f0[j] * c0 + f1[j] * c1 + f2[j] * c2 + f3[j] * c3;
  }
  for (; i < cnt; ++i) {
    int2 s0 = scp[i];
    float c0 = __int_as_float(s0.y);
    float f0[V];
    loadrow(s0.x, f0);
#pragma unroll
    for (int j = 0; j < V; ++j) acc[j] += f0[j] * c0;
  }
  float* op = out + (size_t)v * COLS + lane * V;
  if constexpr (FINALIZE) {
    const float dv = dis[v];
    float d2 = dv * dv;
    float h[V];
    if constexpr (INBF16) {
      const ushort_t* hw = (const ushort_t*)hwv;
      if constexpr (V == 4) {
        ushort4 u = *(const ushort4*)(hw + (size_t)v * COLS + lane * 4);
        h[0] = bf2f(u.x); h[1] = bf2f(u.y); h[2] = bf2f(u.z); h[3] = bf2f(u.w);
      } else {
        h[0] = bf2f(hw[(size_t)v * COLS + lane]);
      }
    } else {
      const float* hw = (const float*)hwv;
      if constexpr (V == 4) {
        float4 q = *(const float4*)(hw + (size_t)v * COLS + lane * 4);
        h[0] = q.x; h[1] = q.y; h[2] = q.z; h[3] = q.w;
      } else {
        h[0] = hw[(size_t)v * COLS + lane];
      }
    }
#pragma unroll
    for (int i2 = 0; i2 < V; ++i2)
      acc[i2] = fmaxf(acc[i2] + h[i2] * d2 + bias[lane * V + i2], 0.f);
  }
  if constexpr (V == 4) {
    *(float4*)op = make_float4(acc[0], acc[1], acc[2], acc[3]);
  } else {
    op[0] = acc[0];
  }
}

// Generic node GEMM: out[r,:NOUT] = inA[r,:K] (+inB[r,:K]*dis[r]^2) @ Wp (+bias, relu)
template <int K, int NOUT, bool COMPOSE, bool RELUBIAS, bool OUTBF16>
__global__ __launch_bounds__(256, 2) void gcn_gemm(
    const float* __restrict__ inA, const float* __restrict__ inB,
    const float* __restrict__ dis,
    const unsigned short* __restrict__ Wp, const float* __restrict__ bias,
    void* __restrict__ outv, int out_stride, int nrows) {
  constexpr int NT = NOUT / 16;
  constexpr int NTW = NOUT / 64;
  __shared__ unsigned short s_in[64 * K];
  const int tid = threadIdx.x;
  const int r0 = blockIdx.x * 64;

  constexpr int C4R = K / 4;
  for (int idx = tid; idx < 64 * C4R; idx += 256) {
    int row = idx / C4R;
    int rem = idx - row * C4R;
    int grow = r0 + row;
    float4 v = make_float4(0.f, 0.f, 0.f, 0.f);
    if (grow < nrows) {
      v = *(const float4*)&inA[(size_t)grow * K + rem * 4];
      if constexpr (COMPOSE) {
        float d = dis[grow];
        d *= d;
        float4 w2 = *(const float4*)&inB[(size_t)grow * K + rem * 4];
        v.x += w2.x * d; v.y += w2.y * d; v.z += w2.z * d; v.w += w2.w * d;
      }
    }
    ushort4 b;
    b.x = f2bf(v.x); b.y = f2bf(v.y); b.z = f2bf(v.z); b.w = f2bf(v.w);
    *(ushort4*)&s_in[row * K + ((rem ^ (row & 7)) * 4)] = b;
  }
  __syncthreads();

  const int lane = tid & 63, wid = tid >> 6;
  const int lr = lane & 15, lg = lane >> 4;
  f32x4 acc[4][NTW];
#pragma unroll
  for (int m = 0; m < 4; ++m)
#pragma unroll
    for (int n2 = 0; n2 < NTW; ++n2) acc[m][n2] = zero4();

#pragma unroll
  for (int kt = 0; kt < K / 32; ++kt) {
    bf16x8 a[4];
#pragma unroll
    for (int m = 0; m < 4; ++m) {
      int rA = m * 16 + lr;
      int c1 = (kt * 8 + lg) ^ (rA & 7);
      int c2 = (kt * 8 + lg + 4) ^ (rA & 7);
      union { bf16x8 v; ull_t q[2]; } u;
      u.q[0] = *(const ull_t*)&s_in[rA * K + c1 * 4];
      u.q[1] = *(const ull_t*)&s_in[rA * K + c2 * 4];
      a[m] = u.v;
    }
#pragma unroll
    for (int n2 = 0; n2 < NTW; ++n2) {
      int nt = wid * NTW + n2;
      bf16x8 b = *(const bf16x8*)&Wp[(((kt * NT + nt) * 64 + lane) * 8)];
#pragma unroll
      for (int m = 0; m < 4; ++m)
        acc[m][n2] = __builtin_amdgcn_mfma_f32_16x16x32_bf16(a[m], b, acc[m][n2], 0, 0, 0);
    }
  }

#pragma unroll
  for (int n2 = 0; n2 < NTW; ++n2) {
    int col = (wid * NTW + n2) * 16 + lr;
    float bv = 0.f;
    if (RELUBIAS) bv = bias[col];
#pragma unroll
    for (int m = 0; m < 4; ++m) {
#pragma unroll
      for (int r = 0; r < 4; ++r) {
        int grow = r0 + m * 16 + lg * 4 + r;
        if (grow < nrows) {
          float v = acc[m][n2][r];
          if (RELUBIAS) v = fmaxf(v + bv, 0.f);
          if constexpr (OUTBF16) {
            ((ushort_t*)outv)[(size_t)grow * out_stride + col] = f2bf(v);
          } else {
            ((float*)outv)[(size_t)grow * out_stride + col] = v;
          }
        }
      }
    }
  }
}

// Fused EdgeConv on dst-sorted edges. 512 threads / 8 waves per 64-edge tile.
// R8 structure + B-fragment double-buffer (hide L2 latency under MFMA) +
// permuted-b64 epi1 with PERMK-compensated W2 pack (proven in R9/R10).
__global__ __launch_bounds__(512, 4) void k_edgeconv(
    const float* __restrict__ x, const float* __restrict__ ea,
    const int2* __restrict__ sc_s, const int* __restrict__ dst_s,
    const int* __restrict__ perm_s,
    const unsigned short* __restrict__ W1p, const float* __restrict__ b1,
    const unsigned short* __restrict__ W2p, const float* __restrict__ b2,
    float* __restrict__ h2, int E) {
  __shared__ unsigned short s_buf[256 * 72];  // 36864 B, aliased across phases
  __shared__ int s_src[64], s_dst[64], s_perm[64];
  __shared__ ull_t s_mask;
  const int tid = threadIdx.x;
  const int e0 = blockIdx.x * 64;
  const int lane = tid & 63, wid = tid >> 6;
  if (tid < 64) {
    int e = e0 + tid;
    s_src[tid] = (e < E) ? sc_s[e].x : 0;
    s_dst[tid] = (e < E) ? dst_s[e] : 0;
    s_perm[tid] = (e < E) ? perm_s[e] : 0;
  }
  __syncthreads();
  if (wid == 0) {
    bool chg = (lane > 0) && (s_dst[lane] != s_dst[lane - 1]);
    ull_t m = __ballot(chg);
    if (lane == 0) s_mask = m;
  }
  // Stage [x_dst | x_src | ea] bf16 into s_buf[row][192], chunk-swizzled.
#pragma unroll
  for (int seg = 0; seg < 3; ++seg) {
#pragma unroll
    for (int it = 0; it < 2; ++it) {
      int idx = it * 512 + tid;
      int ei = idx >> 4;
      int q = idx & 15;
      const float* row;
      if (seg == 0) row = x + (unsigned)s_dst[ei] * 64u;
      else if (seg == 1) row = x + (unsigned)s_src[ei] * 64u;
      else row = ea + (unsigned)s_perm[ei] * 64u;
      float4 v = make_float4(0.f, 0.f, 0.f, 0.f);
      if (e0 + ei < E) v = *(const float4*)(row + q * 4);
      ushort4 b;
      b.x = f2bf(v.x); b.y = f2bf(v.y); b.z = f2bf(v.z); b.w = f2bf(v.w);
      int chunk = (seg * 16 + q) ^ (ei & 7);
      *(ushort4*)&s_buf[ei * 192 + chunk * 4] = b;
    }
  }

  const int wr = wid >> 2;   // 0..1 : row block (32 rows)
  const int wc = wid & 3;    // 0..3 : col block (64 cols)
  const int lr = lane & 15, lg = lane >> 4;

  // Prefetch GEMM1 kt=0 B-frags before the staging barrier (latency cover).
  bf16x8 bn1[4];
#pragma unroll
  for (int n2 = 0; n2 < 4; ++n2)
    bn1[n2] = *(const bf16x8*)&W1p[(((0 * 16 + wc * 4 + n2) * 64 + lane) * 8)];

  __syncthreads();

  f32x4 acc[2][4];
#pragma unroll
  for (int m = 0; m < 2; ++m)
#pragma unroll
    for (int n2 = 0; n2 < 4; ++n2) acc[m][n2] = zero4();

  // GEMM1: K=192, B double-buffered (load kt+1 while MFMAing kt)
#pragma unroll
  for (int kt = 0; kt < 6; ++kt) {
    bf16x8 bc[4];
#pragma unroll
    for (int n2 = 0; n2 < 4; ++n2) bc[n2] = bn1[n2];
    if (kt < 5) {
#pragma unroll
      for (int n2 = 0; n2 < 4; ++n2)
        bn1[n2] = *(const bf16x8*)&W1p[((((kt + 1) * 16 + wc * 4 + n2) * 64 + lane) * 8)];
    }
    bf16x8 a[2];
#pragma unroll
    for (int m = 0; m < 2; ++m) {
      int rA = wr * 32 + m * 16 + lr;
      int rr = rA & 7;
      union { bf16x8 v; ull_t q[2]; } u;
      u.q[0] = *(const ull_t*)&s_buf[rA * 192 + ((kt * 8 + lg) ^ rr) * 4];
      u.q[1] = *(const ull_t*)&s_buf[rA * 192 + ((kt * 8 + lg + 4) ^ rr) * 4];
      a[m] = u.v;
    }
#pragma unroll
    for (int n2 = 0; n2 < 4; ++n2)
#pragma unroll
      for (int m = 0; m < 2; ++m)
        acc[m][n2] = __builtin_amdgcn_mfma_f32_16x16x32_bf16(a[m], bc[n2], acc[m][n2], 0, 0, 0);
  }

  // Prefetch GEMM2 kt=0 B-frags: epi1 + barriers cover their latency.
  bf16x8 bn2[4];
#pragma unroll
  for (int n2 = 0; n2 < 4; ++n2)
    bn2[n2] = *(const bf16x8*)&W2p[(((0 * 16 + wc * 4 + n2) * 64 + lane) * 8)];

  __syncthreads();  // all GEMM1 reads of s_buf done; safe to overwrite

  // hid = relu(acc1 + b1) bf16 -> s_buf[row][256] COL-PERMUTED, b64 writes.
  {
    float b1v[4];
#pragma unroll
    for (int n2 = 0; n2 < 4; ++n2) b1v[n2] = b1[(wc * 4 + n2) * 16 + lr];
#pragma unroll
    for (int m = 0; m < 2; ++m) {
#pragma unroll
      for (int r = 0; r < 4; ++r) {
        int row = wr * 32 + m * 16 + lg * 4 + r;
        union { ushort_t h[4]; ull_t q; } pk;
        pk.h[0] = f2bf(fmaxf(acc[m][0][r] + b1v[0], 0.f));
        pk.h[1] = f2bf(fmaxf(acc[m][1][r] + b1v[1], 0.f));
        pk.h[2] = f2bf(fmaxf(acc[m][2][r] + b1v[2], 0.f));
        pk.h[3] = f2bf(fmaxf(acc[m][3][r] + b1v[3], 0.f));
        int chunk = (wc * 16 + lr) ^ (row & 7);
        *(ull_t*)&s_buf[row * 256 + chunk * 4] = pk.q;
      }
    }
  }
  __syncthreads();

  // GEMM2: K=256 (permuted k-space; W2p pack PERMK-compensates), B dbuf
#pragma unroll
  for (int m = 0; m < 2; ++m)
#pragma unroll
    for (int n2 = 0; n2 < 4; ++n2) acc[m][n2] = zero4();
#pragma unroll
  for (int kt = 0; kt < 8; ++kt) {
    bf16x8 bc[4];
#pragma unroll
    for (int n2 = 0; n2 < 4; ++n2) bc[n2] = bn2[n2];
    if (kt < 7) {
#pragma unroll
      for (int n2 = 0; n2 < 4; ++n2)
        bn2[n2] = *(const bf16x8*)&W2p[((((kt + 1) * 16 + wc * 4 + n2) * 64 + lane) * 8)];
    }
    bf16x8 a[2];
#pragma unroll
    for (int m = 0; m < 2; ++m) {
      int rA = wr * 32 + m * 16 + lr;
      int rr = rA & 7;
      union { bf16x8 v; ull_t q[2]; } u;
      u.q[0] = *(const ull_t*)&s_buf[rA * 256 + ((kt * 8 + lg) ^ rr) * 4];
      u.q[1] = *(const ull_t*)&s_buf[rA * 256 + ((kt * 8 + lg + 4) ^ rr) * 4];
      a[m] = u.v;
    }
#pragma unroll
    for (int n2 = 0; n2 < 4; ++n2)
#pragma unroll
      for (int m = 0; m < 2; ++m)
        acc[m][n2] = __builtin_amdgcn_mfma_f32_16x16x32_bf16(a[m], bc[n2], acc[m][n2], 0, 0, 0);
  }
  __syncthreads();  // all GEMM2 reads done; safe to overwrite

  // m = relu(acc2 + b2) -> TRANSPOSED [col][72] as packed b64 (4 rows/write)
#pragma unroll
  for (int n2 = 0; n2 < 4; ++n2) {
    int col = (wc * 4 + n2) * 16 + lr;
    float bv = b2[col];
#pragma unroll
    for (int m = 0; m < 2; ++m) {
      int rbase = wr * 32 + m * 16 + lg * 4;
      union { ushort_t h[4]; ull_t q; } pk;
#pragma unroll
      for (int r = 0; r < 4; ++r) {
        int row = rbase + r;
        float v = (e0 + row < E) ? fmaxf(acc[m][n2][r] + bv, 0.f) : 0.f;
        pk.h[r] = f2bf(v);
      }
      *(ull_t*)&s_buf[col * 72 + rbase] = pk.q;
    }
  }
  __syncthreads();

  // Segmented max scan in u16 domain: thread = (row-half, column).
  {
    const int col = tid & 255;
    const int half = tid >> 8;
    const int rbeg = half * 32;
    const unsigned int mask = (unsigned int)(s_mask >> rbeg);
    unsigned int run = 0;
    int segstart = rbeg;
#pragma unroll
    for (int i = 0; i < 4; ++i) {
      u16x8 pack = *(const u16x8*)&s_buf[col * 72 + rbeg + i * 8];
#pragma unroll
      for (int r2 = 0; r2 < 8; ++r2) {
        int rloc = i * 8 + r2;
        if (mask & (1u << rloc)) {
          if (run > 0)
            atomicMax((int*)h2 + ((unsigned)s_dst[segstart] * 512u + 256u + col),
                      (int)(run << 16));
          run = 0;
          segstart = rbeg + rloc;
        }
        run = max(run, (unsigned int)pack[r2]);
      }
    }
    if (run > 0)
      atomicMax((int*)h2 + ((unsigned)s_dst[segstart] * 512u + 256u + col),
                (int)(run << 16));
  }
}

// Head MLP: wave-per-node, weights (except W2) staged in LDS.
__global__ __launch_bounds__(256) void k_head(
    const float* __restrict__ x, const float* __restrict__ out3,
    const float* __restrict__ W1, const float* __restrict__ b1,
    const float* __restrict__ W2, const float* __restrict__ b2,
    const float* __restrict__ W3, const float* __restrict__ b3,
    const float* __restrict__ W4, const float* __restrict__ b4,
    float* __restrict__ out, int n) {
  __shared__ float sW1[128 * 64];
  __shared__ float sW3[128 * 32];
  __shared__ float sW4[32 * 2];
  __shared__ float sb1[64], sb2[128], sb3[32], sb4[2];
  __shared__ float sbuf[4][352];
  const int tid = threadIdx.x;
  for (int i = tid; i < 128 * 64; i += 256) sW1[i] = W1[i];
  for (int i = tid; i < 128 * 32; i += 256) sW3[i] = W3[i];
  if (tid < 64) sW4[tid] = W4[tid];
  if (tid < 64) sb1[tid] = b1[tid];
  if (tid < 128) sb2[tid] = b2[tid];
  if (tid < 32) sb3[tid] = b3[tid];
  if (tid < 2) sb4[tid] = b4[tid];
  __syncthreads();
  const int wid = tid >> 6, lane = tid & 63;
  float* B = sbuf[wid];
  const int per = gridDim.x * 4;
  const int iters = (n + per - 1) / per;
  for (int it = 0; it < iters; ++it) {
    const int node = it * per + blockIdx.x * 4 + wid;
    const bool act = node < n;
    if (act) {
      B[lane] = x[(size_t)node * 64 + lane];
      B[64 + lane] = out3[(size_t)node * 64 + lane];
    }
    __syncthreads();
    if (act) {
      float o = sb1[lane];
#pragma unroll 8
      for (int k = 0; k < 128; ++k) o += B[k] * sW1[k * 64 + lane];
      B[128 + lane] = softplusf(o);
    }
    __syncthreads();
    if (act) {
      float o0 = sb2[lane], o1 = sb2[64 + lane];
#pragma unroll 8
      for (int k = 0; k < 64; ++k) {
        float v = B[128 + k];
        o0 += v * W2[k * 128 + lane];
        o1 += v * W2[k * 128 + 64 + lane];
      }
      B[192 + lane] = softplusf(o0);
      B[256 + lane] = softplusf(o1);
    }
    __syncthreads();
    if (act && lane < 32) {
      float o = sb3[lane];
#pragma unroll 8
      for (int k = 0; k < 128; ++k) o += B[192 + k] * sW3[k * 32 + lane];
      B[320 + lane] = softplusf(o);
    }
    __syncthreads();
    if (act && lane < 2) {
      float o = sb4[lane];
#pragma unroll
      for (int k = 0; k < 32; ++k) o += B[320 + k] * sW4[k * 2 + lane];
      out[(size_t)lane * n + node] = o;
    }
    __syncthreads();
  }
}

static inline size_t alignup(size_t v) { return (v + 255) & ~(size_t)255; }

extern "C" void kernel_launch(void* const* d_in, const int* in_sizes, int n_in,
                              void* d_out, int out_size, void* d_ws, size_t ws_size,
                              hipStream_t stream) {
  const float* x = (const float*)d_in[0];
  const int* ei = (const int*)d_in[1];
  const float* ea = (const float*)d_in[2];
  const float* c1W = (const float*)d_in[3];
  const float* c1b = (const float*)d_in[4];
  const float* eW1 = (const float*)d_in[5];
  const float* eb1 = (const float*)d_in[6];
  const float* eW2 = (const float*)d_in[7];
  const float* eb2 = (const float*)d_in[8];
  const float* c2W = (const float*)d_in[9];
  const float* c2b = (const float*)d_in[10];
  const float* c3W = (const float*)d_in[11];
  const float* c3b = (const float*)d_in[12];
  const float* l1W = (const float*)d_in[13];
  const float* l1b = (const float*)d_in[14];
  const float* l2W = (const float*)d_in[15];
  const float* l2b = (const float*)d_in[16];
  const float* l3W = (const float*)d_in[17];
  const float* l3b = (const float*)d_in[18];
  const float* l4W = (const float*)d_in[19];
  const float* l4b = (const float*)d_in[20];
  const int n = in_sizes[0] / 64;
  const int E = in_sizes[1] / 2;
  const int* srcs = ei;
  const int* dsts = ei + E;

  char* w = (char*)d_ws;
  auto alloc = [&](size_t bytes) {
    char* p = w;
    w += alignup(bytes);
    return p;
  };
  float* dis = (float*)alloc((size_t)n * 4);
  int* degi = (int*)alloc((size_t)n * 4);
  int* ptr = (int*)alloc((size_t)(n + 1) * 4);
  int* fillc = (int*)alloc((size_t)n * 4);
  int2* sc_s = (int2*)alloc((size_t)E * 8);
  int* dst_s = (int*)alloc((size_t)E * 4);
  int* perm_s = (int*)alloc((size_t)E * 4);
  float* agg1 = (float*)alloc((size_t)n * 64 * 4);
  float* h2 = (float*)alloc((size_t)n * 512 * 4);          // [out1 | out_e1] f32
  ushort_t* hw2b = (ushort_t*)alloc((size_t)n * 256 * 2);  // bf16
  float* out2 = (float*)alloc((size_t)n * 256 * 4);
  ushort_t* hw3b = (ushort_t*)alloc((size_t)n * 64 * 2);   // bf16
  float* out3 = (float*)alloc((size_t)n * 64 * 4);
  unsigned short* p_c1 = (unsigned short*)alloc(64 * 256 * 2);
  unsigned short* p_e1 = (unsigned short*)alloc(192 * 256 * 2);
  unsigned short* p_e2 = (unsigned short*)alloc(256 * 256 * 2);  // PERMK
  unsigned short* p_c2 = (unsigned short*)alloc(512 * 256 * 2);
  unsigned short* p_c3 = (unsigned short*)alloc(256 * 64 * 2);

  hipMemsetAsync(degi, 0, (size_t)n * 4, stream);
  hipMemsetAsync(fillc, 0, (size_t)n * 4, stream);
  hipMemsetAsync(h2, 0, (size_t)n * 512 * 4, stream);

  pack_weight<<<(64 * 256) / 256, 256, 0, stream>>>(c1W, p_c1, 64, 256, 0);
  pack_weight<<<(192 * 256) / 256, 256, 0, stream>>>(eW1, p_e1, 192, 256, 0);
  pack_weight<<<(256 * 256) / 256, 256, 0, stream>>>(eW2, p_e2, 256, 256, 1);
  pack_weight<<<(512 * 256) / 256, 256, 0, stream>>>(c2W, p_c2, 512, 256, 0);
  pack_weight<<<(256 * 64) / 256, 256, 0, stream>>>(c3W, p_c3, 256, 64, 0);

  // CSR build
  k_deg<<<(E + 255) / 256, 256, 0, stream>>>(dsts, degi, E);
  k_dis<<<(n + 255) / 256, 256, 0, stream>>>(degi, dis, n);
  k_scan<<<1, 1024, 0, stream>>>(degi, ptr, n);
  k_fill<<<(E + 255) / 256, 256, 0, stream>>>(srcs, dsts, ptr, dis, fillc,
                                              sc_s, dst_s, perm_s, E);

  const int ablocks = (n + 3) / 4;
  const int gblocks = (n + 63) / 64;

  // conv1: gather-aggregate x (64 ch, f32), then GEMM with fused self-loop term
  k_gather_agg<64, false, false><<<ablocks, 256, 0, stream>>>(
      x, sc_s, ptr, dis, nullptr, nullptr, agg1, n);
  gcn_gemm<64, 256, true, true, false><<<gblocks, 256, 0, stream>>>(
      agg1, x, dis, p_c1, c1b, h2, 512, n);

  // EdgeConv -> h2[:, 256:512]
  k_edgeconv<<<(E + 63) / 64, 512, 0, stream>>>(x, ea, sc_s, dst_s, perm_s,
                                                p_e1, eb1, p_e2, eb2, h2, E);

  // conv2: matmul (bf16 out) then gather-aggregate (256 ch bf16) + fused finalize
  gcn_gemm<512, 256, false, false, true><<<gblocks, 256, 0, stream>>>(
      h2, nullptr, nullptr, p_c2, nullptr, hw2b, 256, n);
  k_gather_agg<256, true, true><<<ablocks, 256, 0, stream>>>(
      hw2b, sc_s, ptr, dis, hw2b, c2b, out2, n);

  // conv3: matmul (bf16 out) then gather-aggregate (64 ch bf16) + fused finalize
  gcn_gemm<256, 64, false, false, true><<<gblocks, 256, 0, stream>>>(
      out2, nullptr, nullptr, p_c3, nullptr, hw3b, 64, n);
  k_gather_agg<64, true, true><<<ablocks, 256, 0, stream>>>(
      hw3b, sc_s, ptr, dis, hw3b, c3b, out3, n);

  k_head<<<1250, 256, 0, stream>>>(x, out3, l1W, l1b, l2W, l2b, l3W, l3b, l4W, l4b,
                                   (float*)d_out, n);
}